// Round 12
// baseline (71.719 us; speedup 1.0000x reference)
//
#include <hip/hip_runtime.h>
#include <hip/hip_cooperative_groups.h>
#include <stdint.h>

// Detection post-processor, ONE cooperative kernel (80 blocks, 1 per class):
//   phase 1 (all blocks): strided per-class score scan into LDS (L2-served),
//     rank-sort + adjacency-mask greedy NMS + sarr/sidx emission.
//   grid.sync()  (release/acquire across grid; no memset, no manual fences)
//   phase 2 (block 0 only): global top-100 over sarr (histogram select).
// N=2048 proposals, C=81 classes (class 0 dropped).
// Inputs:  d_in[0] = boxes  [2048, 324] f32, d_in[1] = scores [2048, 81] f32
// Output:  d_out = [100, 6] f32 (x1,y1,x2,y2,score,label)
// Workspace (48000 B used; every slot rewritten before the sync each call):
//   [0]     f32 sarr[8000]   per-(class,rank) score (NEGINF pad)
//   [32000] u16 sidx[8000]   proposal index of each kept det

#define NPROP   2048
#define NCLS    81
#define SCORE_T 0.05f
#define NMS_T   0.5f
#define PERCLS  100
#define NREC    (80 * PERCLS)   // 8000
#define NEGINF  -1.0e9f
#define NBIN    4096
#define SELCAP  4096

typedef unsigned long long u64;
typedef unsigned int u32;
typedef unsigned short u16;

namespace cg = cooperative_groups;

__device__ __forceinline__ u32 fflip(float f) {
  u32 u = __float_as_uint(f);
  return (u & 0x80000000u) ? ~u : (u | 0x80000000u);
}
__device__ __forceinline__ float funflip(u32 u) {
  u32 v = (u & 0x80000000u) ? (u ^ 0x80000000u) : ~u;
  return __uint_as_float(v);
}
__device__ __forceinline__ float4 clip_box(float4 r) {
  float4 b;
  b.x = fminf(fmaxf(r.x, 0.f), 1332.f);
  b.y = fminf(fmaxf(r.y, 0.f), 799.f);
  b.z = fminf(fmaxf(r.z, 0.f), 1332.f);
  b.w = fminf(fmaxf(r.w, 0.f), 799.f);
  return b;
}
// Reference IoU (exact expression; symmetric and f32-commutative).
__device__ __forceinline__ float iou_ref(float4 a, float aarea, float4 b,
                                         float barea) {
  float ix1 = fmaxf(a.x, b.x), iy1 = fmaxf(a.y, b.y);
  float ix2 = fminf(a.z, b.z), iy2 = fminf(a.w, b.w);
  float inter = fmaxf(ix2 - ix1, 0.f) * fmaxf(iy2 - iy1, 0.f);
  return inter / (aarea + barea - inter + 1e-9f);
}

// Sort key: [63:32] fflip(score), [31:0] ~proposal_idx. Descending order ==
// (score desc, idx asc) == the reference's stable argsort(-s_masked). Unique,
// so the LDS-atomic append order cannot affect the sorted result.

__global__ __launch_bounds__(256) void fused_kernel(
    const float* __restrict__ boxes, const float* __restrict__ scores,
    float* __restrict__ sarr, u16* __restrict__ sidx,
    float* __restrict__ out) {
  __shared__ __align__(16) char arena[50176];
  // --- class-phase overlay ---
  u64*    keysLds  = (u64*)arena;                   // [2048] 16384 B
  u64*    sortedA  = (u64*)(arena + 16384);         // [256]   2048 B
  float4* bxR      = (float4*)(arena + 18432);      // [256]   4096 B
  float4* keptBx   = (float4*)(arena + 22528);      // [100]   1600 B
  float*  keptArea = (float*)(arena + 24128);       // [100]    400 B
  float4* bxC      = (float4*)(arena + 24576);      // [64]    1024 B
  // --- tail overlay (block 0 only, after grid.sync) ---
  u32*    hist     = (u32*)arena;                   // [4096] 16384 B
  u64*    sel      = (u64*)(arena + 16384);         // [4096] 32768 B
  u64*    selSorted= (u64*)(arena + 49152);         // [128]   1024 B

  __shared__ int mcount, kkOut, selCount;
  __shared__ volatile int sC, sB;
  __shared__ volatile u32 sNeed;

  const int tid = threadIdx.x;
  const int c = blockIdx.x + 1;                     // class 1..80
  const int cls = c - 1;

  if (tid == 0) mcount = 0;
  __syncthreads();

  // ---- Phase 1a: strided per-class scan (8 pipelined loads/thread; the
  // 663 KB score matrix is pulled through L2/LLC and shared by all blocks).
  for (int i = tid; i < NPROP; i += 256) {
    float s = scores[i * NCLS + c];
    if (s > SCORE_T) {
      int slot = atomicAdd(&mcount, 1);
      keysLds[slot] = ((u64)fflip(s) << 32) | (u32)(~(u32)i);
    }
  }
  __syncthreads();
  const int M = mcount;
  const bool fast = (M <= 256);

  if (fast) {
    // Rank sort (one barrier); box gather issued EARLY so it overlaps the
    // rank loop; thread places key+box directly at its own rank.
    if (tid < M) {
      u64 kr = keysLds[tid];
      u32 pi = (~(u32)kr) & (NPROP - 1);
      float4 raw = *(const float4*)(boxes + (size_t)pi * (NCLS * 4) + c * 4);
      int rk = 0;
      for (int j = 0; j < M; ++j) rk += (keysLds[j] > kr) ? 1 : 0;
      sortedA[rk] = kr;
      bxR[rk] = clip_box(raw);
    }
    __syncthreads();
  } else {
    // Slow fallback (correctness only): block bitonic over pow2 P.
    int P = 256; while (P < M) P <<= 1;
    for (int i = M + tid; i < P; i += 256) keysLds[i] = 0ULL;
    __syncthreads();
    for (int k = 2; k <= P; k <<= 1) {
      for (int j = k >> 1; j > 0; j >>= 1) {
        for (int i = tid; i < P; i += 256) {
          int ixj = i ^ j;
          if (ixj > i) {
            u64 a = keysLds[i], b = keysLds[ixj];
            if (((i & k) == 0) ? (a < b) : (a > b)) { keysLds[i] = b; keysLds[ixj] = a; }
          }
        }
        __syncthreads();
      }
    }
  }
  const u64* SK = fast ? sortedA : keysLds;

  float* sbase = sarr + cls * PERCLS;
  u16* ibase = sidx + cls * PERCLS;

  // ---- Phase 1b: greedy NMS, adjacency-mask form (wave 0 only). Semantics
  // identical to greedy: dies iff an earlier KEPT candidate has IoU > thresh.
  if (tid < 64) {
    const int lane = tid;
    int kkTot = 0;
    const int NC = (M + 63) >> 6;
    for (int q = 0; q < NC && kkTot < PERCLS; ++q) {
      const int cbase = q << 6;
      const int ccnt = min(64, M - cbase);
      u64 mykey = 0ULL;
      float4 b = make_float4(0.f, 0.f, 0.f, 0.f);
      int alive = 0;
      if (lane < ccnt) {
        mykey = SK[cbase + lane];
        if (fast) {
          b = bxR[cbase + lane];
        } else {
          u32 pi = ~(u32)mykey;
          b = clip_box(*(const float4*)(boxes + (size_t)pi * (NCLS * 4) + c * 4));
        }
        alive = 1;
      }
      bxC[lane] = b;                       // stage chunk boxes (wave-sync)
      const float barea = fmaxf(b.z - b.x, 0.f) * fmaxf(b.w - b.y, 0.f);
      __builtin_amdgcn_wave_barrier();

      // (0) cross-chunk: dead if any already-kept box overlaps me.
      for (int t = 0; t < kkTot; ++t) {
        float4 kb = keptBx[t];
        if (iou_ref(kb, keptArea[t], b, barea) > NMS_T) alive = 0;
      }

      // (a) intra-chunk suppression row: bits j > lane with IoU > thresh.
      u64 supRow = 0ULL;
      for (int j = 0; j < ccnt; ++j) {
        float4 ob = bxC[j];                // LDS broadcast
        float oarea = fmaxf(ob.z - ob.x, 0.f) * fmaxf(ob.w - ob.y, 0.f);
        bool hit = (j > lane) && (iou_ref(b, barea, ob, oarea) > NMS_T);
        supRow |= (u64)(hit ? 1u : 0u) << j;
      }
      const u32 rowLo = (u32)supRow, rowHi = (u32)(supRow >> 32);

      // (b) scalar propagation over alive candidates in rank order.
      u64 work = __ballot(alive != 0);
      u64 kept = 0ULL;
      while (work) {
        int i = (int)__builtin_ctzll(work);
        u32 rl = __builtin_amdgcn_readlane(rowLo, i);
        u32 rh = __builtin_amdgcn_readlane(rowHi, i);
        kept |= 1ull << i;
        work &= ~(((u64)rh << 32) | rl);
        work &= work - 1;                  // clear bit i
      }

      // cap at PERCLS kept per class (trim highest ranks; then we stop).
      int budget = PERCLS - kkTot;
      int over = (int)__popcll(kept) - budget;
      while (over-- > 0) kept &= ~(1ull << (63 - __builtin_clzll(kept)));

      // (c) parallel emission in rank order.
      if ((kept >> lane) & 1ull) {
        int rank = kkTot + (int)__popcll(kept & ((1ull << lane) - 1ull));
        sbase[rank] = funflip((u32)(mykey >> 32));
        ibase[rank] = (u16)(~(u32)mykey);
        keptBx[rank] = b;
        keptArea[rank] = barea;
      }
      kkTot += (int)__popcll(kept);
      __builtin_amdgcn_wave_barrier();
    }
    if (lane == 0) kkOut = kkTot;
  }
  __syncthreads();

  // Pad remaining slots (every sarr/sidx slot is written every call).
  for (int slot = kkOut + tid; slot < PERCLS; slot += 256) {
    sbase[slot] = NEGINF;
    ibase[slot] = 0;
  }

  // ---- Grid-wide sync: all blocks' sarr/sidx stores visible after this.
  cg::this_grid().sync();
  if (blockIdx.x != 0) return;

  // ---- Phase 2 (block 0): global top-100 ----
  for (int b = tid; b < NBIN; b += 256) hist[b] = 0;
  if (tid == 0) { selCount = 0; sC = 0; sNeed = 1; sB = 0; }
  if (tid < 128) selSorted[tid] = 0ULL;
  __syncthreads();

  // Histogram. Bucket = bits [26:15] of fflip(score): kept scores in
  // (0.05,1] share fflip's top 5 bits (0b10111) so bucket order == score
  // order; NEGINF pads fail the tag test and are skipped.
  const float4* s4p = (const float4*)sarr;
  for (int e4 = tid; e4 < NREC / 4; e4 += 256) {
    float4 s4 = s4p[e4];
    #pragma unroll
    for (int t = 0; t < 4; ++t) {
      float sv = (t == 0) ? s4.x : (t == 1) ? s4.y : (t == 2) ? s4.z : s4.w;
      u32 k32 = fflip(sv);
      if ((k32 >> 27) == 0x17u) atomicAdd(&hist[(k32 >> 15) & 0xFFFu], 1);
    }
  }
  __syncthreads();

  // Wave 0: find bucket B containing the 100th-largest kept score.
  if (tid < 64) {
    const int lane = tid;
    u32 p = 0;
    for (int t = 0; t < 64; ++t) p += hist[lane * 64 + t];
    u32 S = p;                               // inclusive suffix over chunks
    for (int off = 1; off < 64; off <<= 1) {
      u32 v = __shfl_down(S, off, 64);
      if (lane + off < 64) S += v;
    }
    u32 Sn = __shfl_down(S, 1, 64);
    if (lane == 63) Sn = 0;
    if (S >= 100u && Sn < 100u) { sC = lane; sNeed = 100u - Sn; }
    __builtin_amdgcn_wave_barrier();
    const int C = sC;
    const u32 need2 = sNeed;
    u32 T = hist[C * 64 + lane];             // inclusive suffix over bins
    for (int off = 1; off < 64; off <<= 1) {
      u32 v = __shfl_down(T, off, 64);
      if (lane + off < 64) T += v;
    }
    u32 Tn = __shfl_down(T, 1, 64);
    if (lane == 63) Tn = 0;
    if (T >= need2 && Tn < need2) sB = C * 64 + lane;
    __builtin_amdgcn_wave_barrier();
  }
  __syncthreads();
  const int B = sB;

  // Compact entries with bucket >= B (typically ~110-200).
  for (int e4 = tid; e4 < NREC / 4; e4 += 256) {
    float4 s4 = s4p[e4];
    #pragma unroll
    for (int t = 0; t < 4; ++t) {
      float sv = (t == 0) ? s4.x : (t == 1) ? s4.y : (t == 2) ? s4.z : s4.w;
      u32 k32 = fflip(sv);
      if ((k32 >> 27) == 0x17u && (int)((k32 >> 15) & 0xFFFu) >= B) {
        int slot = atomicAdd(&selCount, 1);
        int e = e4 * 4 + t;
        if (slot < SELCAP) sel[slot] = ((u64)k32 << 32) | (u32)(~(u32)e);
      }
    }
  }
  __syncthreads();
  const int CB = min(selCount, SELCAP);

  // Rank-select the top 100 (keys unique via ~e; tie order == lowest flat
  // index first, matching lax.top_k — (class, rank) lex order is preserved).
  for (int r = tid; r < CB; r += 256) {
    u64 kr2 = sel[r];
    int rk = 0;
    for (int j = 0; j < CB; ++j) rk += (sel[j] > kr2) ? 1 : 0;
    if (rk < PERCLS) selSorted[rk] = kr2;
  }
  __syncthreads();

  if (tid < PERCLS) {
    u64 key = selSorted[tid];
    float* o = out + tid * 6;
    if (key != 0ULL) {
      u32 e = ~(u32)key;
      int wc = (int)(e / PERCLS) + 1;        // class label from entry index
      u32 pi = sidx[e];
      // Re-gather + re-clip the winner's box (bitwise-identical clip).
      float4 b = clip_box(*(const float4*)(boxes + (size_t)pi * (NCLS * 4) + wc * 4));
      o[0] = b.x; o[1] = b.y; o[2] = b.z; o[3] = b.w;
      o[4] = funflip((u32)(key >> 32));
      o[5] = (float)wc;
    } else {
      // only reachable if fewer than 100 detections survive globally
      o[0] = 0.f; o[1] = 0.f; o[2] = 0.f; o[3] = 0.f; o[4] = NEGINF; o[5] = 0.f;
    }
  }
}

extern "C" void kernel_launch(void* const* d_in, const int* in_sizes, int n_in,
                              void* d_out, int out_size, void* d_ws, size_t ws_size,
                              hipStream_t stream) {
  const float* boxes  = (const float*)d_in[0];   // [2048, 324]
  const float* scores = (const float*)d_in[1];   // [2048, 81]
  char* ws = (char*)d_ws;
  float* sarr = (float*)ws;                      // [0, 32000)
  u16*   sidx = (u16*)(ws + 32000);              // [32000, 48000)
  float* out  = (float*)d_out;                   // [100, 6]

  void* args[] = {(void*)&boxes, (void*)&scores, (void*)&sarr,
                  (void*)&sidx, (void*)&out};
  hipLaunchCooperativeKernel((void*)fused_kernel, dim3(80), dim3(256),
                             args, 0, stream);
}

// Round 13
// 47.734 us; speedup vs baseline: 1.5025x; 1.5025x over previous
//
#include <hip/hip_runtime.h>
#include <stdint.h>

// Detection post-processor, two kernels, no memset node (best: R11, 48.1 µs):
//  A (80 blocks, 1/class): strided per-class score scan into LDS (L2-served),
//    rank-sort + adjacency-mask greedy NMS + sarr/sidx emission.
//  B (1 block): global top-100 over sarr (histogram select) + output.
// N=2048 proposals, C=81 classes (class 0 dropped).
// Inputs:  d_in[0] = boxes  [2048, 324] f32, d_in[1] = scores [2048, 81] f32
// Output:  d_out = [100, 6] f32 (x1,y1,x2,y2,score,label)
// Workspace (48000 B used; every slot rewritten each call, no init needed):
//   [0]     f32 sarr[8000]   per-(class,rank) score (NEGINF pad)
//   [32000] u16 sidx[8000]   proposal index of each kept det

#define NPROP   2048
#define NCLS    81
#define SCORE_T 0.05f
#define NMS_T   0.5f
#define PERCLS  100
#define NREC    (80 * PERCLS)   // 8000
#define NEGINF  -1.0e9f
#define NBIN    4096
#define SELCAP  4096

typedef unsigned long long u64;
typedef unsigned int u32;
typedef unsigned short u16;

__device__ __forceinline__ u32 fflip(float f) {
  u32 u = __float_as_uint(f);
  return (u & 0x80000000u) ? ~u : (u | 0x80000000u);
}
__device__ __forceinline__ float funflip(u32 u) {
  u32 v = (u & 0x80000000u) ? (u ^ 0x80000000u) : ~u;
  return __uint_as_float(v);
}
__device__ __forceinline__ float4 clip_box(float4 r) {
  float4 b;
  b.x = fminf(fmaxf(r.x, 0.f), 1332.f);
  b.y = fminf(fmaxf(r.y, 0.f), 799.f);
  b.z = fminf(fmaxf(r.z, 0.f), 1332.f);
  b.w = fminf(fmaxf(r.w, 0.f), 799.f);
  return b;
}
// Reference IoU (exact expression; symmetric and f32-commutative).
__device__ __forceinline__ float iou_ref(float4 a, float aarea, float4 b,
                                         float barea) {
  float ix1 = fmaxf(a.x, b.x), iy1 = fmaxf(a.y, b.y);
  float ix2 = fminf(a.z, b.z), iy2 = fminf(a.w, b.w);
  float inter = fmaxf(ix2 - ix1, 0.f) * fmaxf(iy2 - iy1, 0.f);
  return inter / (aarea + barea - inter + 1e-9f);
}

// Sort key: [63:32] fflip(score), [31:0] ~proposal_idx. Descending order ==
// (score desc, idx asc) == the reference's stable argsort(-s_masked). Unique,
// so the LDS-atomic append order cannot affect the sorted result.

// ---- Kernel A: per-class scan + sort + mask-NMS + emission. ----
__global__ __launch_bounds__(256) void nms_kernel(
    const float* __restrict__ boxes, const float* __restrict__ scores,
    float* __restrict__ sarr, u16* __restrict__ sidx) {
  __shared__ u64 keysLds[NPROP];       // 16 KB
  __shared__ u64 sortedA[256];         //  2 KB (fast path M<=256)
  __shared__ float4 bxR[256];          //  4 KB rank-indexed boxes
  __shared__ float4 keptBx[PERCLS];
  __shared__ float keptArea[PERCLS];
  __shared__ float4 bxC[64];
  __shared__ int mcount, kkOut;

  const int tid = threadIdx.x;
  const int c = blockIdx.x + 1;                     // class 1..80
  const int cls = c - 1;

  if (tid == 0) mcount = 0;
  __syncthreads();

  // Strided per-class scan: 8 pipelined loads/thread. The 663 KB score
  // matrix is pulled through L2/LLC once and shared by all 80 blocks.
  for (int i = tid; i < NPROP; i += 256) {
    float s = scores[i * NCLS + c];
    if (s > SCORE_T) {
      int slot = atomicAdd(&mcount, 1);
      keysLds[slot] = ((u64)fflip(s) << 32) | (u32)(~(u32)i);
    }
  }
  __syncthreads();
  const int M = mcount;
  const bool fast = (M <= 256);

  if (fast) {
    // Rank sort (one barrier); box gather issued EARLY so it overlaps the
    // rank loop; thread places key+box directly at its own rank.
    if (tid < M) {
      u64 kr = keysLds[tid];
      u32 pi = (~(u32)kr) & (NPROP - 1);
      float4 raw = *(const float4*)(boxes + (size_t)pi * (NCLS * 4) + c * 4);
      int rk = 0;
      for (int j = 0; j < M; ++j) rk += (keysLds[j] > kr) ? 1 : 0;
      sortedA[rk] = kr;
      bxR[rk] = clip_box(raw);
    }
    __syncthreads();
  } else {
    // Slow fallback (correctness only): block bitonic over pow2 P.
    int P = 256; while (P < M) P <<= 1;
    for (int i = M + tid; i < P; i += 256) keysLds[i] = 0ULL;
    __syncthreads();
    for (int k = 2; k <= P; k <<= 1) {
      for (int j = k >> 1; j > 0; j >>= 1) {
        for (int i = tid; i < P; i += 256) {
          int ixj = i ^ j;
          if (ixj > i) {
            u64 a = keysLds[i], b = keysLds[ixj];
            if (((i & k) == 0) ? (a < b) : (a > b)) { keysLds[i] = b; keysLds[ixj] = a; }
          }
        }
        __syncthreads();
      }
    }
  }
  const u64* SK = fast ? sortedA : keysLds;

  float* sbase = sarr + cls * PERCLS;
  u16* ibase = sidx + cls * PERCLS;

  // ---- Greedy NMS, adjacency-mask form (wave 0 only). Semantics identical
  // to greedy: a candidate dies iff an earlier KEPT candidate has IoU>thresh.
  if (tid < 64) {
    const int lane = tid;
    int kkTot = 0;
    const int NC = (M + 63) >> 6;
    for (int q = 0; q < NC && kkTot < PERCLS; ++q) {
      const int cbase = q << 6;
      const int ccnt = min(64, M - cbase);
      u64 mykey = 0ULL;
      float4 b = make_float4(0.f, 0.f, 0.f, 0.f);
      int alive = 0;
      if (lane < ccnt) {
        mykey = SK[cbase + lane];
        if (fast) {
          b = bxR[cbase + lane];
        } else {
          u32 pi = ~(u32)mykey;
          b = clip_box(*(const float4*)(boxes + (size_t)pi * (NCLS * 4) + c * 4));
        }
        alive = 1;
      }
      bxC[lane] = b;                       // stage chunk boxes (wave-sync)
      const float barea = fmaxf(b.z - b.x, 0.f) * fmaxf(b.w - b.y, 0.f);
      __builtin_amdgcn_wave_barrier();

      // (0) cross-chunk: dead if any already-kept box overlaps me.
      for (int t = 0; t < kkTot; ++t) {
        float4 kb = keptBx[t];
        if (iou_ref(kb, keptArea[t], b, barea) > NMS_T) alive = 0;
      }

      // (a) intra-chunk suppression row: bits j > lane with IoU > thresh.
      u64 supRow = 0ULL;
      for (int j = 0; j < ccnt; ++j) {
        float4 ob = bxC[j];                // LDS broadcast
        float oarea = fmaxf(ob.z - ob.x, 0.f) * fmaxf(ob.w - ob.y, 0.f);
        bool hit = (j > lane) && (iou_ref(b, barea, ob, oarea) > NMS_T);
        supRow |= (u64)(hit ? 1u : 0u) << j;
      }
      const u32 rowLo = (u32)supRow, rowHi = (u32)(supRow >> 32);

      // (b) scalar propagation over alive candidates in rank order.
      u64 work = __ballot(alive != 0);
      u64 kept = 0ULL;
      while (work) {
        int i = (int)__builtin_ctzll(work);
        u32 rl = __builtin_amdgcn_readlane(rowLo, i);
        u32 rh = __builtin_amdgcn_readlane(rowHi, i);
        kept |= 1ull << i;
        work &= ~(((u64)rh << 32) | rl);
        work &= work - 1;                  // clear bit i
      }

      // cap at PERCLS kept per class (trim highest ranks; then we stop).
      int budget = PERCLS - kkTot;
      int over = (int)__popcll(kept) - budget;
      while (over-- > 0) kept &= ~(1ull << (63 - __builtin_clzll(kept)));

      // (c) parallel emission in rank order.
      if ((kept >> lane) & 1ull) {
        int rank = kkTot + (int)__popcll(kept & ((1ull << lane) - 1ull));
        sbase[rank] = funflip((u32)(mykey >> 32));
        ibase[rank] = (u16)(~(u32)mykey);
        keptBx[rank] = b;
        keptArea[rank] = barea;
      }
      kkTot += (int)__popcll(kept);
      __builtin_amdgcn_wave_barrier();
    }
    if (lane == 0) kkOut = kkTot;
  }
  __syncthreads();

  // Pad remaining slots (every sarr/sidx slot is written every call).
  for (int slot = kkOut + tid; slot < PERCLS; slot += 256) {
    sbase[slot] = NEGINF;
    ibase[slot] = 0;
  }
}

// ---- Kernel B: global top-100 (1 block). Kernel boundary = ordering. ----
__global__ __launch_bounds__(256) void topk_kernel(
    const float* __restrict__ boxes, const float* __restrict__ sarr,
    const u16* __restrict__ sidx, float* __restrict__ out) {
  __shared__ u32 hist[NBIN];           // 16 KB
  __shared__ u64 sel[SELCAP];          // 32 KB
  __shared__ u64 selSorted[128];       //  1 KB
  __shared__ int selCount;
  __shared__ volatile int sC, sB;
  __shared__ volatile u32 sNeed;
  const int tid = threadIdx.x;

  for (int b = tid; b < NBIN; b += 256) hist[b] = 0;
  if (tid == 0) { selCount = 0; sC = 0; sNeed = 1; sB = 0; }
  if (tid < 128) selSorted[tid] = 0ULL;
  __syncthreads();

  // Histogram. Bucket = bits [26:15] of fflip(score): kept scores in
  // (0.05,1] share fflip's top 5 bits (0b10111) so bucket order == score
  // order; NEGINF pads fail the tag test and are skipped.
  const float4* s4p = (const float4*)sarr;
  for (int e4 = tid; e4 < NREC / 4; e4 += 256) {
    float4 s4 = s4p[e4];
    #pragma unroll
    for (int t = 0; t < 4; ++t) {
      float sv = (t == 0) ? s4.x : (t == 1) ? s4.y : (t == 2) ? s4.z : s4.w;
      u32 k32 = fflip(sv);
      if ((k32 >> 27) == 0x17u) atomicAdd(&hist[(k32 >> 15) & 0xFFFu], 1);
    }
  }
  __syncthreads();

  // Wave 0: find bucket B containing the 100th-largest kept score.
  if (tid < 64) {
    const int lane = tid;
    u32 p = 0;
    for (int t = 0; t < 64; ++t) p += hist[lane * 64 + t];
    u32 S = p;                               // inclusive suffix over chunks
    for (int off = 1; off < 64; off <<= 1) {
      u32 v = __shfl_down(S, off, 64);
      if (lane + off < 64) S += v;
    }
    u32 Sn = __shfl_down(S, 1, 64);
    if (lane == 63) Sn = 0;
    if (S >= 100u && Sn < 100u) { sC = lane; sNeed = 100u - Sn; }
    __builtin_amdgcn_wave_barrier();
    const int C = sC;
    const u32 need2 = sNeed;
    u32 T = hist[C * 64 + lane];             // inclusive suffix over bins
    for (int off = 1; off < 64; off <<= 1) {
      u32 v = __shfl_down(T, off, 64);
      if (lane + off < 64) T += v;
    }
    u32 Tn = __shfl_down(T, 1, 64);
    if (lane == 63) Tn = 0;
    if (T >= need2 && Tn < need2) sB = C * 64 + lane;
    __builtin_amdgcn_wave_barrier();
  }
  __syncthreads();
  const int B = sB;

  // Compact entries with bucket >= B (typically ~110-200).
  for (int e4 = tid; e4 < NREC / 4; e4 += 256) {
    float4 s4 = s4p[e4];
    #pragma unroll
    for (int t = 0; t < 4; ++t) {
      float sv = (t == 0) ? s4.x : (t == 1) ? s4.y : (t == 2) ? s4.z : s4.w;
      u32 k32 = fflip(sv);
      if ((k32 >> 27) == 0x17u && (int)((k32 >> 15) & 0xFFFu) >= B) {
        int slot = atomicAdd(&selCount, 1);
        int e = e4 * 4 + t;
        if (slot < SELCAP) sel[slot] = ((u64)k32 << 32) | (u32)(~(u32)e);
      }
    }
  }
  __syncthreads();
  const int CB = min(selCount, SELCAP);

  // Rank-select the top 100 (keys unique via ~e; tie order == lowest flat
  // index first, matching lax.top_k — (class, rank) lex order is preserved).
  for (int r = tid; r < CB; r += 256) {
    u64 kr2 = sel[r];
    int rk = 0;
    for (int j = 0; j < CB; ++j) rk += (sel[j] > kr2) ? 1 : 0;
    if (rk < PERCLS) selSorted[rk] = kr2;
  }
  __syncthreads();

  if (tid < PERCLS) {
    u64 key = selSorted[tid];
    float* o = out + tid * 6;
    if (key != 0ULL) {
      u32 e = ~(u32)key;
      int wc = (int)(e / PERCLS) + 1;        // class label from entry index
      u32 pi = sidx[e];
      // Re-gather + re-clip the winner's box (bitwise-identical clip).
      float4 b = clip_box(*(const float4*)(boxes + (size_t)pi * (NCLS * 4) + wc * 4));
      o[0] = b.x; o[1] = b.y; o[2] = b.z; o[3] = b.w;
      o[4] = funflip((u32)(key >> 32));
      o[5] = (float)wc;
    } else {
      // only reachable if fewer than 100 detections survive globally
      o[0] = 0.f; o[1] = 0.f; o[2] = 0.f; o[3] = 0.f; o[4] = NEGINF; o[5] = 0.f;
    }
  }
}

extern "C" void kernel_launch(void* const* d_in, const int* in_sizes, int n_in,
                              void* d_out, int out_size, void* d_ws, size_t ws_size,
                              hipStream_t stream) {
  const float* boxes  = (const float*)d_in[0];   // [2048, 324]
  const float* scores = (const float*)d_in[1];   // [2048, 81]
  char* ws = (char*)d_ws;
  float* sarr = (float*)ws;                      // [0, 32000)
  u16*   sidx = (u16*)(ws + 32000);              // [32000, 48000)
  float* out  = (float*)d_out;                   // [100, 6]

  nms_kernel<<<80, 256, 0, stream>>>(boxes, scores, sarr, sidx);
  topk_kernel<<<1, 256, 0, stream>>>(boxes, sarr, sidx, out);
}